// Round 5
// baseline (787.957 us; speedup 1.0000x reference)
//
#include <hip/hip_runtime.h>
#include <hip/hip_bf16.h>

#define B_ 4
#define P_ 1024
#define G_ 1024
#define L_ 2048
#define D_ 512
#define FF_ 2048
#define H_ 8
#define DH_ 64
#define LAYERS_ 4
#define LN_EPS_ 1e-5f

typedef __attribute__((ext_vector_type(8))) short bf16x8;
typedef __attribute__((ext_vector_type(4))) float f32x4;

__device__ __forceinline__ ushort f2b(float f) {
  unsigned u = __float_as_uint(f);
  unsigned r = (u + 0x7fffu + ((u >> 16) & 1u)) >> 16;
  return (ushort)r;
}
__device__ __forceinline__ float b2f(ushort u) {
  return __uint_as_float(((unsigned)u) << 16);
}

// async 16B global->LDS (DMA; dest = wave-uniform base + lane*16)
__device__ __forceinline__ void gld16(const ushort* g, ushort* l) {
  __builtin_amdgcn_global_load_lds(
      (const __attribute__((address_space(1))) void*)g,
      (__attribute__((address_space(3))) void*)l, 16, 0, 0);
}

// ---------------- concat pcpt+gen -> x (fp32) + xbf (bf16) ----------------
__global__ __launch_bounds__(256) void concat_kernel(const float* __restrict__ p,
    const float* __restrict__ g, float* __restrict__ x, ushort* __restrict__ xb)
{
  const int LD4 = L_*D_/4, PD4 = P_*D_/4;
  int i = blockIdx.x*256 + threadIdx.x;
  int b = i / LD4, r = i - b*LD4;
  float4 v;
  if (r < PD4) v = ((const float4*)p)[(size_t)b*PD4 + r];
  else         v = ((const float4*)g)[(size_t)b*PD4 + (r-PD4)];
  ((float4*)x)[i] = v;
  ushort4 h; h.x=f2b(v.x); h.y=f2b(v.y); h.z=f2b(v.z); h.w=f2b(v.w);
  ((ushort4*)xb)[i] = h;
}

// ---------------- writeout ----------------
__global__ __launch_bounds__(256) void writeout_kernel(const float* __restrict__ x,
    float* __restrict__ out)
{
  const int LD4 = L_*D_/4, PD4 = P_*D_/4, HALF = B_*PD4;
  int i = blockIdx.x*256 + threadIdx.x;
  int half = (i >= HALF) ? 1 : 0;
  int r = i - half*HALF;
  int b = r / PD4, q = r - b*PD4;
  ((float4*)out)[i] = ((const float4*)x)[(size_t)b*LD4 + half*PD4 + q];
}

// ---------------- weight transpose+convert: src K x N fp32 -> dst N x K bf16 ----------------
__global__ __launch_bounds__(256) void wconv_kernel(const float* __restrict__ src,
    ushort* __restrict__ dst, int K, int N)
{
  __shared__ float tile[32][33];
  int n0 = blockIdx.x*32, k0 = blockIdx.y*32, l = blockIdx.z;
  src += (size_t)l*K*N; dst += (size_t)l*K*N;
  int tx = threadIdx.x & 31, ty = threadIdx.x >> 5;
  #pragma unroll
  for (int u=0;u<4;++u) tile[ty+8*u][tx] = src[(size_t)(k0+ty+8*u)*N + n0+tx];
  __syncthreads();
  #pragma unroll
  for (int u=0;u<4;++u) dst[(size_t)(n0+ty+8*u)*K + k0+tx] = f2b(tile[tx][ty+8*u]);
}

// ---------------- bf16 MFMA GEMM, BN_ in {128,64}, BM=128, BK=64 ----------------
// SERIAL 2-barrier structure (r3-proven). r4's 2-phase double-buffer variant
// REGRESSED here: wo/w1/w2 run at 5-6 blocks/CU (grid 512, small LDS) so TLP
// already hides the stage latency; doubling LDS for the pipeline halved
// occupancy and cost ~80us across the layer loop. Pipelining pays only where
// TLP is absent (see mgemm_qkv below, grid 768 -> ~16% occ).
template<int BN_, int RELU, int RES, int OUTBF>
__global__ __launch_bounds__(256) void mgemm(
    const ushort* __restrict__ A, const ushort* __restrict__ Bt,
    const float* __restrict__ bias, const float* __restrict__ res,
    void* __restrict__ Cout, int M, int N, int K)
{
  constexpr int MI = (BN_ == 128) ? 4 : 2;
  constexpr int BL = BN_ / 32;               // B loader row-groups
  __shared__ ushort As[128*64];
  __shared__ ushort Bs[BN_*64];
  int t = threadIdx.x;
  int lane = t & 63, w = t >> 6;
  int wm = (BN_ == 128) ? (w >> 1) * 64 : w * 32;
  int wn = (BN_ == 128) ? (w & 1) * 64 : 0;
  int m0 = blockIdx.x * 128, n0 = blockIdx.y * BN_;

  f32x4 acc[MI][4] = {};

  int rbase = t >> 3;                        // 0..31
  int cch   = (t & 7) ^ ((t >> 3) & 7);      // swizzled chunk col (L-invariant)
  const ushort* Ag = A  + (size_t)(m0 + rbase)*K + cch*8;
  const ushort* Bg = Bt + (size_t)(n0 + rbase)*K + cch*8;
  ushort* Asl = As + t*8;
  ushort* Bsl = Bs + t*8;
  const size_t rowK32 = (size_t)32 * K;

  int fr = lane & 15, fq = lane >> 4;
  int swr[2];
  swr[0] = ((0*4 + fq) ^ (fr & 7)) * 8;
  swr[1] = ((1*4 + fq) ^ (fr & 7)) * 8;
  const ushort* Ard = As + (wm + fr)*64;
  const ushort* Brd = Bs + (wn + fr)*64;

  for (int k0 = 0; k0 < K; k0 += 64) {
    __syncthreads();
    #pragma unroll
    for (int L = 0; L < 4; ++L)  gld16(Ag + L*rowK32, Asl + L*2048);
    #pragma unroll
    for (int L = 0; L < BL; ++L) gld16(Bg + L*rowK32, Bsl + L*2048);
    Ag += 64; Bg += 64;
    __syncthreads();
    #pragma unroll
    for (int s = 0; s < 2; ++s) {
      int sw = swr[s];
      bf16x8 af[MI], bfr[4];
      #pragma unroll
      for (int i=0;i<MI;++i) af[i]  = *(const bf16x8*)(Ard + i*16*64 + sw);
      #pragma unroll
      for (int j=0;j<4;++j)  bfr[j] = *(const bf16x8*)(Brd + j*16*64 + sw);
      #pragma unroll
      for (int i=0;i<MI;++i)
        #pragma unroll
        for (int j=0;j<4;++j)
          acc[i][j] = __builtin_amdgcn_mfma_f32_16x16x32_bf16(af[i], bfr[j], acc[i][j], 0, 0, 0);
    }
  }

  int ncol = lane & 15;
  int rquad = (lane >> 4) * 4;
  #pragma unroll
  for (int j=0;j<4;++j) {
    int n = n0 + wn + j*16 + ncol;
    float bv = bias[n];
    #pragma unroll
    for (int i=0;i<MI;++i) {
      int mbase = m0 + wm + i*16 + rquad;
      #pragma unroll
      for (int r=0;r<4;++r) {
        int m = mbase + r;
        float c = acc[i][j][r] + bv;
        if (RES) c += res[(size_t)m*N + n];
        if (RELU) c = fmaxf(c, 0.f);
        if (OUTBF) ((ushort*)Cout)[(size_t)m*N + n] = f2b(c);
        else       ((float*)Cout)[(size_t)m*N + n] = c;
      }
    }
  }
}

// ---------------- QKV GEMM, 2-phase prefetch pipeline (r4-proven win) -------
// Grid 768 blocks -> ~3 blocks/CU, TLP-poor: within-wave pipelining is the
// lever here (qkv 64.5 -> <40us in r4). LDS double-buffered; per K-step:
//   vmcnt(0); s_barrier; sched_barrier; STAGE(next tile, other buf); compute(cur)
__global__ __launch_bounds__(256) void mgemm_qkv(
    const ushort* __restrict__ A,    // M x 512 bf16 (x)
    const ushort* __restrict__ Bt,   // 1536 x 512 bf16
    const float* __restrict__ bias,  // 1536
    ushort* __restrict__ qb,         // [b,h,l,64]  (pre-scaled by 0.125)
    ushort* __restrict__ kb,         // [b,h,l,64]
    ushort* __restrict__ vtb)        // [b,h,64,l]
{
  const int K = D_;
  __shared__ ushort As[2*128*64];
  __shared__ ushort Bs[2*128*64];
  int t = threadIdx.x;
  int lane = t & 63, w = t >> 6;
  int wm = (w >> 1) * 64, wn = (w & 1) * 64;
  int m0 = blockIdx.x * 128, n0 = blockIdx.y * 128;

  f32x4 acc[4][4] = {};

  int rbase = t >> 3;
  int cch   = (t & 7) ^ ((t >> 3) & 7);
  const ushort* Ag = A  + (size_t)(m0 + rbase)*K + cch*8;
  const ushort* Bg = Bt + (size_t)(n0 + rbase)*K + cch*8;
  ushort* Asl0 = As + t*8;
  ushort* Asl1 = As + 128*64 + t*8;
  ushort* Bsl0 = Bs + t*8;
  ushort* Bsl1 = Bs + 128*64 + t*8;
  const size_t rowK32 = (size_t)32 * K;

  int fr = lane & 15, fq = lane >> 4;
  int swr[2];
  swr[0] = ((0*4 + fq) ^ (fr & 7)) * 8;
  swr[1] = ((1*4 + fq) ^ (fr & 7)) * 8;

  // prologue: stage tile 0 into buffer 0
  #pragma unroll
  for (int L = 0; L < 4; ++L) gld16(Ag + L*rowK32, Asl0 + L*2048);
  #pragma unroll
  for (int L = 0; L < 4; ++L) gld16(Bg + L*rowK32, Bsl0 + L*2048);

  const int NT = K >> 6;
  for (int tt = 0; tt < NT; ++tt) {
    asm volatile("s_waitcnt vmcnt(0)" ::: "memory");
    __builtin_amdgcn_s_barrier();
    __builtin_amdgcn_sched_barrier(0);
    if (tt + 1 < NT) {
      const ushort* Agn = Ag + (size_t)(tt+1)*64;
      const ushort* Bgn = Bg + (size_t)(tt+1)*64;
      ushort* Ad = (tt & 1) ? Asl0 : Asl1;
      ushort* Bd = (tt & 1) ? Bsl0 : Bsl1;
      #pragma unroll
      for (int L = 0; L < 4; ++L) gld16(Agn + L*rowK32, Ad + L*2048);
      #pragma unroll
      for (int L = 0; L < 4; ++L) gld16(Bgn + L*rowK32, Bd + L*2048);
    }
    const ushort* Ard = ((tt & 1) ? As + 128*64 : As) + (wm + fr)*64;
    const ushort* Brd = ((tt & 1) ? Bs + 128*64 : Bs) + (wn + fr)*64;
    #pragma unroll
    for (int s = 0; s < 2; ++s) {
      int sw = swr[s];
      bf16x8 af[4], bfr[4];
      #pragma unroll
      for (int i=0;i<4;++i) af[i]  = *(const bf16x8*)(Ard + i*16*64 + sw);
      #pragma unroll
      for (int j=0;j<4;++j) bfr[j] = *(const bf16x8*)(Brd + j*16*64 + sw);
      #pragma unroll
      for (int i=0;i<4;++i)
        #pragma unroll
        for (int j=0;j<4;++j)
          acc[i][j] = __builtin_amdgcn_mfma_f32_16x16x32_bf16(af[i], bfr[j], acc[i][j], 0, 0, 0);
    }
  }

  int ncol = lane & 15;
  int rquad = (lane >> 4) * 4;
  #pragma unroll
  for (int j=0;j<4;++j) {
    int n = n0 + wn + j*16 + ncol;
    float bv = bias[n];
    int part = n >> 9;            // 0=q 1=k 2=v (block-uniform: 128 | 512)
    int wi = n & 511;
    int h = wi >> 6, d = wi & 63;
    #pragma unroll
    for (int i=0;i<4;++i) {
      int mbase = m0 + wm + i*16 + rquad;
      #pragma unroll
      for (int r=0;r<4;++r) {
        int m = mbase + r;
        int b = m >> 11, l = m & 2047;
        int bh = b*H_ + h;
        float cv = acc[i][j][r] + bv;
        if (part == 0) cv *= 0.125f;       // fold 1/sqrt(dh) into q
        ushort c = f2b(cv);
        if (part == 0)      qb[((size_t)bh*L_ + l)*DH_ + d] = c;
        else if (part == 1) kb[((size_t)bh*L_ + l)*DH_ + d] = c;
        else                vtb[((size_t)bh*DH_ + d)*L_ + l] = c;
      }
    }
  }
}

// ---------------- MFMA flash attention: QBLK=128, swizzled K/V LDS ----------
__global__ __launch_bounds__(256) void attn_mfma(
    const ushort* __restrict__ qb, const ushort* __restrict__ kb,
    const ushort* __restrict__ vtb, ushort* __restrict__ outa)
{
  __shared__ ushort Ks[2][64*64];
  __shared__ ushort Vts[2][64*64];
  __shared__ ushort Ps[8*16*72];    // 4 waves x 2 subtiles

  int t = threadIdx.x;
  int lane = t & 63, w = t >> 6;
  int qt = blockIdx.x & 15;
  int h  = (blockIdx.x >> 4) & 7;
  int b  = blockIdx.x >> 7;
  int l0 = qt * 128;
  bool isgen = (l0 >= P_);
  int bh = b*H_ + h;

  const ushort* qg  = qb  + ((size_t)bh*L_ + l0)*DH_;
  const ushort* kgb = kb  + (size_t)bh*L_*DH_;
  const ushort* vtg = vtb + (size_t)bh*DH_*L_;

  int sr  = t >> 3;                       // staging row 0..31 (row+32 same &7)
  int scg = (t & 7) * 8;                  // global col (ushorts)
  int scs = ((t & 7) ^ (sr & 7)) * 8;     // swizzled LDS col

  int fr = lane & 15, fq = lane >> 4;
  int swz0 = ((0*4 + fq) ^ (fr & 7)) * 8; // fragment chunk, s=0
  int swz1 = ((1*4 + fq) ^ (fr & 7)) * 8; // fragment chunk, s=1

  // Q fragments: 2 subtiles x 2 k-halves
  bf16x8 qf[2][2];
  #pragma unroll
  for (int i=0;i<2;++i) {
    qf[i][0] = *(const bf16x8*)(qg + (size_t)(w*32 + i*16 + fr)*DH_ + fq*8);
    qf[i][1] = *(const bf16x8*)(qg + (size_t)(w*32 + i*16 + fr)*DH_ + 32 + fq*8);
  }

  float den[2][4] = {};
  f32x4 o[2][4] = {};
  ushort* Pw0 = Ps + (w*2 + 0)*16*72;
  ushort* Pw1 = Ps + (w*2 + 1)*16*72;

  // stage tile 0 into buffer 0 (linear global src, swizzled LDS dest)
  {
    uint4 a0 = *(const uint4*)(kgb + (size_t)sr*DH_ + scg);
    uint4 a1 = *(const uint4*)(kgb + (size_t)(sr+32)*DH_ + scg);
    uint4 a2 = *(const uint4*)(vtg + (size_t)sr*L_ + scg);
    uint4 a3 = *(const uint4*)(vtg + (size_t)(sr+32)*L_ + scg);
    *(uint4*)(&Ks[0][sr*64 + scs])       = a0;
    *(uint4*)(&Ks[0][(sr+32)*64 + scs])  = a1;
    *(uint4*)(&Vts[0][sr*64 + scs])      = a2;
    *(uint4*)(&Vts[0][(sr+32)*64 + scs]) = a3;
  }
  // register prefetch of tile 1
  uint4 pk0 = *(const uint4*)(kgb + (size_t)(64+sr)*DH_ + scg);
  uint4 pk1 = *(const uint4*)(kgb + (size_t)(64+sr+32)*DH_ + scg);
  uint4 pv0 = *(const uint4*)(vtg + (size_t)sr*L_ + 64 + scg);
  uint4 pv1 = *(const uint4*)(vtg + (size_t)(sr+32)*L_ + 64 + scg);
  __syncthreads();

  for (int kt = 0; kt < 16; ++kt) {
    const ushort* Kc = &Ks[kt & 1][0];
    const ushort* Vc = &Vts[kt & 1][0];
    if (kt < 15) {
      ushort* Kn = &Ks[(kt+1) & 1][0];
      ushort* Vn = &Vts[(kt+1) & 1][0];
      *(uint4*)(Kn + sr*64 + scs)      = pk0;
      *(uint4*)(Kn + (sr+32)*64 + scs) = pk1;
      *(uint4*)(Vn + sr*64 + scs)      = pv0;
      *(uint4*)(Vn + (sr+32)*64 + scs) = pv1;
    }
    if (kt < 14) {
      int p2 = (kt + 2) * 64;
      pk0 = *(const uint4*)(kgb + (size_t)(p2+sr)*DH_ + scg);
      pk1 = *(const uint4*)(kgb + (size_t)(p2+sr+32)*DH_ + scg);
      pv0 = *(const uint4*)(vtg + (size_t)sr*L_ + p2 + scg);
      pv1 = *(const uint4*)(vtg + (size_t)(sr+32)*L_ + p2 + scg);
    }

    f32x4 sc4[2][4] = {};
    __builtin_amdgcn_s_setprio(1);
    #pragma unroll
    for (int s=0;s<2;++s) {
      int sw = s ? swz1 : swz0;
      #pragma unroll
      for (int j=0;j<4;++j) {
        bf16x8 kf = *(const bf16x8*)(Kc + (j*16 + fr)*64 + sw);
        sc4[0][j] = __builtin_amdgcn_mfma_f32_16x16x32_bf16(qf[0][s], kf, sc4[0][j], 0, 0, 0);
        sc4[1][j] = __builtin_amdgcn_mfma_f32_16x16x32_bf16(qf[1][s], kf, sc4[1][j], 0, 0, 0);
      }
    }
    __builtin_amdgcn_s_setprio(0);

    #pragma unroll
    for (int i=0;i<2;++i) {
      ushort* Pw = i ? Pw1 : Pw0;
      #pragma unroll
      for (int r=0;r<4;++r) {
        float e0 = __expf(sc4[i][0][r]);
        float e1 = __expf(sc4[i][1][r]);
        float e2 = __expf(sc4[i][2][r]);
        float e3 = __expf(sc4[i][3][r]);
        den[i][r] += (e0+e1) + (e2+e3);
        Pw[(fq*4+r)*72 +  0 + fr] = (ushort)(__float_as_uint(e0) >> 16);
        Pw[(fq*4+r)*72 + 16 + fr] = (ushort)(__float_as_uint(e1) >> 16);
        Pw[(fq*4+r)*72 + 32 + fr] = (ushort)(__float_as_uint(e2) >> 16);
        Pw[(fq*4+r)*72 + 48 + fr] = (ushort)(__float_as_uint(e3) >> 16);
      }
    }
    asm volatile("s_waitcnt lgkmcnt(0)" ::: "memory");

    __builtin_amdgcn_s_setprio(1);
    #pragma unroll
    for (int s=0;s<2;++s) {
      int sw = s ? swz1 : swz0;
      bf16x8 pf0 = *(const bf16x8*)(Pw0 + fr*72 + s*32 + fq*8);
      bf16x8 pf1 = *(const bf16x8*)(Pw1 + fr*72 + s*32 + fq*8);
      #pragma unroll
      for (int j=0;j<4;++j) {
        bf16x8 vf = *(const bf16x8*)(Vc + (j*16 + fr)*64 + sw);
        o[0][j] = __builtin_amdgcn_mfma_f32_16x16x32_bf16(pf0, vf, o[0][j], 0, 0, 0);
        o[1][j] = __builtin_amdgcn_mfma_f32_16x16x32_bf16(pf1, vf, o[1][j], 0, 0, 0);
      }
    }
    __builtin_amdgcn_s_setprio(0);
    __syncthreads();
  }

  #pragma unroll
  for (int i=0;i<2;++i)
    #pragma unroll
    for (int r=0;r<4;++r) {
      float d = den[i][r];
      d += __shfl_xor(d, 1, 16);
      d += __shfl_xor(d, 2, 16);
      d += __shfl_xor(d, 4, 16);
      d += __shfl_xor(d, 8, 16);
      den[i][r] = d;
    }

  if (isgen) {
    // diagonal q.k via one 16x16 MFMA pair per subtile; diag S[m][m] lives in
    // lane fq*16+m (m = fq*4+r), register r. Broadcast with per-lane shfl.
    #pragma unroll
    for (int i=0;i<2;++i) {
      int base = l0 + w*32 + i*16;
      f32x4 dsc = {};
      {
        bf16x8 kd0 = *(const bf16x8*)(kgb + (size_t)(base + fr)*DH_ + fq*8);
        dsc = __builtin_amdgcn_mfma_f32_16x16x32_bf16(qf[i][0], kd0, dsc, 0, 0, 0);
        bf16x8 kd1 = *(const bf16x8*)(kgb + (size_t)(base + fr)*DH_ + 32 + fq*8);
        dsc = __builtin_amdgcn_mfma_f32_16x16x32_bf16(qf[i][1], kd1, dsc, 0, 0, 0);
      }
      #pragma unroll
      for (int r=0;r<4;++r) {
        int m = fq*4 + r;
        float dl = __shfl(dsc[r], fq*16 + m);
        float ed = __expf(dl);
        den[i][r] += ed;
        int l = base + m;
        #pragma unroll
        for (int j=0;j<4;++j) {
          float vv = b2f(vtg[(size_t)(j*16 + fr)*L_ + l]);
          o[i][j][r] += ed*vv;
        }
      }
    }
  }

  #pragma unroll
  for (int i=0;i<2;++i)
    #pragma unroll
    for (int r=0;r<4;++r) {
      float inv = 1.f / den[i][r];
      int l = l0 + w*32 + i*16 + fq*4 + r;
      #pragma unroll
      for (int j=0;j<4;++j)
        outa[((size_t)b*L_ + l)*D_ + h*DH_ + j*16 + fr] = f2b(o[i][j][r]*inv);
    }
}

// ---------------- LayerNorm -> x fp32 + xbf bf16 ----------------
__global__ __launch_bounds__(64) void ln_kernel(const float* __restrict__ y,
    const float* __restrict__ gw, const float* __restrict__ bw,
    float* __restrict__ x, ushort* __restrict__ xb)
{
  int row = blockIdx.x, t = threadIdx.x;
  const float4* yr = (const float4*)(y + (size_t)row*D_);
  float4 v0 = yr[t], v1 = yr[t+64];
  float s = v0.x+v0.y+v0.z+v0.w + v1.x+v1.y+v1.z+v1.w;
  for (int off=32; off>0; off>>=1) s += __shfl_down(s, off, 64);
  s = __shfl(s, 0, 64);
  float mu = s * (1.f/D_);
  float dx;
  float q = 0.f;
  dx=v0.x-mu; q+=dx*dx; dx=v0.y-mu; q+=dx*dx; dx=v0.z-mu; q+=dx*dx; dx=v0.w-mu; q+=dx*dx;
  dx=v1.x-mu; q+=dx*dx; dx=v1.y-mu; q+=dx*dx; dx=v1.z-mu; q+=dx*dx; dx=v1.w-mu; q+=dx*dx;
  for (int off=32; off>0; off>>=1) q += __shfl_down(q, off, 64);
  q = __shfl(q, 0, 64);
  float rinv = rsqrtf(q*(1.f/D_) + LN_EPS_);
  const float4* g4 = (const float4*)gw;
  const float4* b4 = (const float4*)bw;
  float4 gv0=g4[t], gv1=g4[t+64], bv0=b4[t], bv1=b4[t+64];
  float4 o0, o1;
  o0.x=(v0.x-mu)*rinv*gv0.x+bv0.x; o0.y=(v0.y-mu)*rinv*gv0.y+bv0.y;
  o0.z=(v0.z-mu)*rinv*gv0.z+bv0.z; o0.w=(v0.w-mu)*rinv*gv0.w+bv0.w;
  o1.x=(v1.x-mu)*rinv*gv1.x+bv1.x; o1.y=(v1.y-mu)*rinv*gv1.y+bv1.y;
  o1.z=(v1.z-mu)*rinv*gv1.z+bv1.z; o1.w=(v1.w-mu)*rinv*gv1.w+bv1.w;
  float4* xr = (float4*)(x + (size_t)row*D_);
  xr[t]=o0; xr[t+64]=o1;
  ushort4 h0, h1;
  h0.x=f2b(o0.x); h0.y=f2b(o0.y); h0.z=f2b(o0.z); h0.w=f2b(o0.w);
  h1.x=f2b(o1.x); h1.y=f2b(o1.y); h1.z=f2b(o1.z); h1.w=f2b(o1.w);
  ushort4* xbr = (ushort4*)(xb + (size_t)row*D_);
  xbr[t]=h0; xbr[t+64]=h1;
}

extern "C" void kernel_launch(void* const* d_in, const int* in_sizes, int n_in,
                              void* d_out, int out_size, void* d_ws, size_t ws_size,
                              hipStream_t stream) {
  const float* pcpt = (const float*)d_in[0];
  const float* gen  = (const float*)d_in[1];
  const float* Wqkv = (const float*)d_in[3];
  const float* bqkv = (const float*)d_in[4];
  const float* Wo   = (const float*)d_in[5];
  const float* bo   = (const float*)d_in[6];
  const float* W1   = (const float*)d_in[7];
  const float* b1   = (const float*)d_in[8];
  const float* W2   = (const float*)d_in[9];
  const float* b2   = (const float*)d_in[10];
  const float* g1   = (const float*)d_in[11];
  const float* be1  = (const float*)d_in[12];
  const float* g2   = (const float*)d_in[13];
  const float* be2  = (const float*)d_in[14];
  float* out = (float*)d_out;

  const size_t XD  = (size_t)B_*L_*D_;
  const size_t HKV = (size_t)B_*H_*L_*DH_;
  const size_t HFF = (size_t)B_*L_*FF_;

  float*  xbuf = (float*)d_ws;
  ushort* xbf  = (ushort*)(xbuf + XD);
  ushort* region = xbf + XD;
  ushort* qb  = region;                        // aliased with hbf
  ushort* kb  = region + HKV;
  ushort* vtb = region + 2*HKV;
  ushort* hbf = region;
  ushort* abf = region + HFF;
  ushort* wb  = abf + XD;
  ushort* wqkv_b = wb;
  ushort* wo_b   = wqkv_b + (size_t)4*3*D_*D_;
  ushort* w1_b   = wo_b   + (size_t)4*D_*D_;
  ushort* w2_b   = w1_b   + (size_t)4*FF_*D_;
  float*  ybuf = out;

  const int M = B_*L_;

  wconv_kernel<<<dim3(3*D_/32, D_/32, 4), 256, 0, stream>>>(Wqkv, wqkv_b, D_, 3*D_);
  wconv_kernel<<<dim3(D_/32,   D_/32, 4), 256, 0, stream>>>(Wo,   wo_b,   D_, D_);
  wconv_kernel<<<dim3(FF_/32,  D_/32, 4), 256, 0, stream>>>(W1,   w1_b,   D_, FF_);
  wconv_kernel<<<dim3(D_/32,  FF_/32, 4), 256, 0, stream>>>(W2,   w2_b,   FF_, D_);

  concat_kernel<<<4096, 256, 0, stream>>>(pcpt, gen, xbuf, xbf);

  for (int i = 0; i < LAYERS_; ++i) {
    const ushort* wqkv_i = wqkv_b + (size_t)i*3*D_*D_;
    const ushort* wo_i   = wo_b   + (size_t)i*D_*D_;
    const ushort* w1_i   = w1_b   + (size_t)i*FF_*D_;
    const ushort* w2_i   = w2_b   + (size_t)i*D_*FF_;
    const float* bqkv_i = bqkv + (size_t)i*3*D_;
    const float* bo_i   = bo   + (size_t)i*D_;
    const float* b1_i   = b1   + (size_t)i*FF_;
    const float* b2_i   = b2   + (size_t)i*D_;
    const float* g1_i   = g1   + (size_t)i*D_;
    const float* be1_i  = be1  + (size_t)i*D_;
    const float* g2_i   = g2   + (size_t)i*D_;
    const float* be2_i  = be2  + (size_t)i*D_;

    // grid: (m-tiles, n-tiles) -> n-tiles of an m-band share an XCD
    mgemm_qkv<<<dim3(M/128, 3*D_/128), 256, 0, stream>>>(
        xbf, wqkv_i, bqkv_i, qb, kb, vtb);

    attn_mfma<<<B_*H_*(L_/128), 256, 0, stream>>>(qb, kb, vtb, abf);

    mgemm<64,0,1,0><<<dim3(M/128, D_/64), 256, 0, stream>>>(
        abf, wo_i, bo_i, xbuf, ybuf, M, D_, D_);

    ln_kernel<<<M, 64, 0, stream>>>(ybuf, g1_i, be1_i, xbuf, xbf);

    mgemm<128,1,0,1><<<dim3(M/128, FF_/128), 256, 0, stream>>>(
        xbf, w1_i, b1_i, nullptr, hbf, M, FF_, D_);

    mgemm<64,0,1,0><<<dim3(M/128, D_/64), 256, 0, stream>>>(
        hbf, w2_i, b2_i, xbuf, ybuf, M, D_, FF_);

    ln_kernel<<<M, 64, 0, stream>>>(ybuf, g2_i, be2_i, xbuf, xbf);
  }

  writeout_kernel<<<4096, 256, 0, stream>>>(xbuf, out);
}

// Round 6
// 751.364 us; speedup vs baseline: 1.0487x; 1.0487x over previous
//
#include <hip/hip_runtime.h>
#include <hip/hip_bf16.h>

#define B_ 4
#define P_ 1024
#define G_ 1024
#define L_ 2048
#define D_ 512
#define FF_ 2048
#define H_ 8
#define DH_ 64
#define LAYERS_ 4
#define LN_EPS_ 1e-5f

typedef __attribute__((ext_vector_type(8))) short bf16x8;
typedef __attribute__((ext_vector_type(4))) float f32x4;

__device__ __forceinline__ ushort f2b(float f) {
  unsigned u = __float_as_uint(f);
  unsigned r = (u + 0x7fffu + ((u >> 16) & 1u)) >> 16;
  return (ushort)r;
}
__device__ __forceinline__ float b2f(ushort u) {
  return __uint_as_float(((unsigned)u) << 16);
}

// async 16B global->LDS (DMA; dest = wave-uniform base + lane*16)
__device__ __forceinline__ void gld16(const ushort* g, ushort* l) {
  __builtin_amdgcn_global_load_lds(
      (const __attribute__((address_space(1))) void*)g,
      (__attribute__((address_space(3))) void*)l, 16, 0, 0);
}

// ---------------- concat pcpt+gen -> x (fp32) + xbf (bf16) ----------------
__global__ __launch_bounds__(256) void concat_kernel(const float* __restrict__ p,
    const float* __restrict__ g, float* __restrict__ x, ushort* __restrict__ xb)
{
  const int LD4 = L_*D_/4, PD4 = P_*D_/4;
  int i = blockIdx.x*256 + threadIdx.x;
  int b = i / LD4, r = i - b*LD4;
  float4 v;
  if (r < PD4) v = ((const float4*)p)[(size_t)b*PD4 + r];
  else         v = ((const float4*)g)[(size_t)b*PD4 + (r-PD4)];
  ((float4*)x)[i] = v;
  ushort4 h; h.x=f2b(v.x); h.y=f2b(v.y); h.z=f2b(v.z); h.w=f2b(v.w);
  ((ushort4*)xb)[i] = h;
}

// ---------------- writeout ----------------
__global__ __launch_bounds__(256) void writeout_kernel(const float* __restrict__ x,
    float* __restrict__ out)
{
  const int LD4 = L_*D_/4, PD4 = P_*D_/4, HALF = B_*PD4;
  int i = blockIdx.x*256 + threadIdx.x;
  int half = (i >= HALF) ? 1 : 0;
  int r = i - half*HALF;
  int b = r / PD4, q = r - b*PD4;
  ((float4*)out)[i] = ((const float4*)x)[(size_t)b*LD4 + half*PD4 + q];
}

// ---------------- weight transpose+convert: src K x N fp32 -> dst N x K bf16 ----------------
__global__ __launch_bounds__(256) void wconv_kernel(const float* __restrict__ src,
    ushort* __restrict__ dst, int K, int N)
{
  __shared__ float tile[32][33];
  int n0 = blockIdx.x*32, k0 = blockIdx.y*32, l = blockIdx.z;
  src += (size_t)l*K*N; dst += (size_t)l*K*N;
  int tx = threadIdx.x & 31, ty = threadIdx.x >> 5;
  #pragma unroll
  for (int u=0;u<4;++u) tile[ty+8*u][tx] = src[(size_t)(k0+ty+8*u)*N + n0+tx];
  __syncthreads();
  #pragma unroll
  for (int u=0;u<4;++u) dst[(size_t)(n0+ty+8*u)*K + k0+tx] = f2b(tile[tx][ty+8*u]);
}

// ---------------- bf16 MFMA GEMM, 2-phase prefetch pipeline (r4-best) -------
// Per K-step: vmcnt(0); s_barrier; sched_barrier; STAGE(next, other buf);
// compute(cur). r4 (all-pipelined) measured 782.7us vs r5 serial 788.0 ->
// pipelined kept everywhere.
template<int BN_, int RELU, int RES, int OUTBF>
__global__ __launch_bounds__(256) void mgemm(
    const ushort* __restrict__ A, const ushort* __restrict__ Bt,
    const float* __restrict__ bias, const float* __restrict__ res,
    void* __restrict__ Cout, int M, int N, int K)
{
  constexpr int MI = (BN_ == 128) ? 4 : 2;
  constexpr int BL = BN_ / 32;               // B loader row-groups
  __shared__ ushort As[2*128*64];
  __shared__ ushort Bs[2*BN_*64];
  int t = threadIdx.x;
  int lane = t & 63, w = t >> 6;
  int wm = (BN_ == 128) ? (w >> 1) * 64 : w * 32;
  int wn = (BN_ == 128) ? (w & 1) * 64 : 0;
  int m0 = blockIdx.x * 128, n0 = blockIdx.y * BN_;

  f32x4 acc[MI][4] = {};

  int rbase = t >> 3;                        // 0..31
  int cch   = (t & 7) ^ ((t >> 3) & 7);      // swizzled chunk col (L-invariant)
  const ushort* Ag = A  + (size_t)(m0 + rbase)*K + cch*8;
  const ushort* Bg = Bt + (size_t)(n0 + rbase)*K + cch*8;
  ushort* Asl0 = As + t*8;
  ushort* Asl1 = As + 128*64 + t*8;
  ushort* Bsl0 = Bs + t*8;
  ushort* Bsl1 = Bs + BN_*64 + t*8;
  const size_t rowK32 = (size_t)32 * K;

  int fr = lane & 15, fq = lane >> 4;
  int swr[2];
  swr[0] = ((0*4 + fq) ^ (fr & 7)) * 8;
  swr[1] = ((1*4 + fq) ^ (fr & 7)) * 8;

  // prologue: stage tile 0 into buffer 0
  #pragma unroll
  for (int L = 0; L < 4; ++L)  gld16(Ag + L*rowK32, Asl0 + L*2048);
  #pragma unroll
  for (int L = 0; L < BL; ++L) gld16(Bg + L*rowK32, Bsl0 + L*2048);

  const int NT = K >> 6;
  for (int tt = 0; tt < NT; ++tt) {
    asm volatile("s_waitcnt vmcnt(0)" ::: "memory");
    __builtin_amdgcn_s_barrier();
    __builtin_amdgcn_sched_barrier(0);
    if (tt + 1 < NT) {
      const ushort* Agn = Ag + (size_t)(tt+1)*64;
      const ushort* Bgn = Bg + (size_t)(tt+1)*64;
      ushort* Ad = (tt & 1) ? Asl0 : Asl1;   // tile tt+1 -> buffer (tt+1)&1
      ushort* Bd = (tt & 1) ? Bsl0 : Bsl1;
      #pragma unroll
      for (int L = 0; L < 4; ++L)  gld16(Agn + L*rowK32, Ad + L*2048);
      #pragma unroll
      for (int L = 0; L < BL; ++L) gld16(Bgn + L*rowK32, Bd + L*2048);
    }
    const ushort* Ard = ((tt & 1) ? As + 128*64 : As) + (wm + fr)*64;
    const ushort* Brd = ((tt & 1) ? Bs + BN_*64 : Bs) + (wn + fr)*64;
    #pragma unroll
    for (int s = 0; s < 2; ++s) {
      int sw = swr[s];
      bf16x8 af[MI], bfr[4];
      #pragma unroll
      for (int i=0;i<MI;++i) af[i]  = *(const bf16x8*)(Ard + i*16*64 + sw);
      #pragma unroll
      for (int j=0;j<4;++j)  bfr[j] = *(const bf16x8*)(Brd + j*16*64 + sw);
      #pragma unroll
      for (int i=0;i<MI;++i)
        #pragma unroll
        for (int j=0;j<4;++j)
          acc[i][j] = __builtin_amdgcn_mfma_f32_16x16x32_bf16(af[i], bfr[j], acc[i][j], 0, 0, 0);
    }
  }

  int ncol = lane & 15;
  int rquad = (lane >> 4) * 4;
  #pragma unroll
  for (int j=0;j<4;++j) {
    int n = n0 + wn + j*16 + ncol;
    float bv = bias[n];
    #pragma unroll
    for (int i=0;i<MI;++i) {
      int mbase = m0 + wm + i*16 + rquad;
      #pragma unroll
      for (int r=0;r<4;++r) {
        int m = mbase + r;
        float c = acc[i][j][r] + bv;
        if (RES) c += res[(size_t)m*N + n];
        if (RELU) c = fmaxf(c, 0.f);
        if (OUTBF) ((ushort*)Cout)[(size_t)m*N + n] = f2b(c);
        else       ((float*)Cout)[(size_t)m*N + n] = c;
      }
    }
  }
}

// ---------------- QKV GEMM, 2-phase pipeline + LDS-transposed v store -------
// v-part blocks (n0>=1024, block-uniform) previously wrote vtb with 2-byte
// scattered stores (d varies per lane, stride L_ rows) -> 16 transactions per
// wave-store. Fix: dump the 128x128 tile into LDS [nrel][mrel] (row stride
// 136 ushorts: pad breaks row alignment -> <=2-way write aliasing, aligned
// b128 reads) and store coalesced 16B chunks along l. 8x fewer v-store
// transactions. q/k path unchanged.
__global__ __launch_bounds__(256) void mgemm_qkv(
    const ushort* __restrict__ A,    // M x 512 bf16 (x)
    const ushort* __restrict__ Bt,   // 1536 x 512 bf16
    const float* __restrict__ bias,  // 1536
    ushort* __restrict__ qb,         // [b,h,l,64]  (pre-scaled by 0.125)
    ushort* __restrict__ kb,         // [b,h,l,64]
    ushort* __restrict__ vtb)        // [b,h,64,l]
{
  const int K = D_;
  __shared__ ushort SMEM[4*128*64];     // As dbuf | Bs dbuf; reused as T
  ushort* As = SMEM;
  ushort* Bs = SMEM + 2*128*64;
  int t = threadIdx.x;
  int lane = t & 63, w = t >> 6;
  int wm = (w >> 1) * 64, wn = (w & 1) * 64;
  int m0 = blockIdx.x * 128, n0 = blockIdx.y * 128;

  f32x4 acc[4][4] = {};

  int rbase = t >> 3;
  int cch   = (t & 7) ^ ((t >> 3) & 7);
  const ushort* Ag = A  + (size_t)(m0 + rbase)*K + cch*8;
  const ushort* Bg = Bt + (size_t)(n0 + rbase)*K + cch*8;
  ushort* Asl0 = As + t*8;
  ushort* Asl1 = As + 128*64 + t*8;
  ushort* Bsl0 = Bs + t*8;
  ushort* Bsl1 = Bs + 128*64 + t*8;
  const size_t rowK32 = (size_t)32 * K;

  int fr = lane & 15, fq = lane >> 4;
  int swr[2];
  swr[0] = ((0*4 + fq) ^ (fr & 7)) * 8;
  swr[1] = ((1*4 + fq) ^ (fr & 7)) * 8;

  // prologue: stage tile 0 into buffer 0
  #pragma unroll
  for (int L = 0; L < 4; ++L) gld16(Ag + L*rowK32, Asl0 + L*2048);
  #pragma unroll
  for (int L = 0; L < 4; ++L) gld16(Bg + L*rowK32, Bsl0 + L*2048);

  const int NT = K >> 6;
  for (int tt = 0; tt < NT; ++tt) {
    asm volatile("s_waitcnt vmcnt(0)" ::: "memory");
    __builtin_amdgcn_s_barrier();
    __builtin_amdgcn_sched_barrier(0);
    if (tt + 1 < NT) {
      const ushort* Agn = Ag + (size_t)(tt+1)*64;
      const ushort* Bgn = Bg + (size_t)(tt+1)*64;
      ushort* Ad = (tt & 1) ? Asl0 : Asl1;
      ushort* Bd = (tt & 1) ? Bsl0 : Bsl1;
      #pragma unroll
      for (int L = 0; L < 4; ++L) gld16(Agn + L*rowK32, Ad + L*2048);
      #pragma unroll
      for (int L = 0; L < 4; ++L) gld16(Bgn + L*rowK32, Bd + L*2048);
    }
    const ushort* Ard = ((tt & 1) ? As + 128*64 : As) + (wm + fr)*64;
    const ushort* Brd = ((tt & 1) ? Bs + 128*64 : Bs) + (wn + fr)*64;
    #pragma unroll
    for (int s = 0; s < 2; ++s) {
      int sw = swr[s];
      bf16x8 af[4], bfr[4];
      #pragma unroll
      for (int i=0;i<4;++i) af[i]  = *(const bf16x8*)(Ard + i*16*64 + sw);
      #pragma unroll
      for (int j=0;j<4;++j) bfr[j] = *(const bf16x8*)(Brd + j*16*64 + sw);
      #pragma unroll
      for (int i=0;i<4;++i)
        #pragma unroll
        for (int j=0;j<4;++j)
          acc[i][j] = __builtin_amdgcn_mfma_f32_16x16x32_bf16(af[i], bfr[j], acc[i][j], 0, 0, 0);
    }
  }

  int ncol = lane & 15;
  int rquad = (lane >> 4) * 4;

  if (n0 < 1024) {
    // ---- q/k path: 32B-chunk coalesced scalar stores (unchanged) ----
    #pragma unroll
    for (int j=0;j<4;++j) {
      int n = n0 + wn + j*16 + ncol;
      float bv = bias[n];
      int part = n >> 9;            // 0=q 1=k (block-uniform)
      int wi = n & 511;
      int h = wi >> 6, d = wi & 63;
      #pragma unroll
      for (int i=0;i<4;++i) {
        int mbase = m0 + wm + i*16 + rquad;
        #pragma unroll
        for (int r=0;r<4;++r) {
          int m = mbase + r;
          int b = m >> 11, l = m & 2047;
          int bh = b*H_ + h;
          float cv = acc[i][j][r] + bv;
          if (part == 0) cv *= 0.125f;       // fold 1/sqrt(dh) into q
          ushort c = f2b(cv);
          if (part == 0) qb[((size_t)bh*L_ + l)*DH_ + d] = c;
          else           kb[((size_t)bh*L_ + l)*DH_ + d] = c;
        }
      }
    }
  } else {
    // ---- v path: transpose via LDS, coalesced 16B stores along l ----
    __syncthreads();                   // all waves done reading As/Bs
    ushort* T = SMEM;                  // [128 nrel][136] (pad 8)
    #pragma unroll
    for (int j=0;j<4;++j) {
      int nrel = wn + j*16 + ncol;
      float bv = bias[n0 + nrel];
      #pragma unroll
      for (int i=0;i<4;++i) {
        #pragma unroll
        for (int r=0;r<4;++r) {
          int mrel = wm + i*16 + rquad + r;
          T[nrel*136 + mrel] = f2b(acc[i][j][r] + bv);
        }
      }
    }
    __syncthreads();
    int b = m0 >> 11, l0r = m0 & 2047;
    int wi0 = n0 & 511;
    #pragma unroll
    for (int u = 0; u < 8; ++u) {
      int idx = u*256 + t;             // 0..2047
      int row = idx >> 4, mc = idx & 15;
      uint4 val = *(const uint4*)(T + row*136 + mc*8);
      int wi = wi0 + row;
      int h = wi >> 6, d = wi & 63;
      int bh = b*H_ + h;
      *(uint4*)(vtb + ((size_t)bh*DH_ + d)*L_ + l0r + mc*8) = val;
    }
  }
}

// ---------------- MFMA flash attention: QBLK=128, swizzled K/V LDS ----------
__global__ __launch_bounds__(256) void attn_mfma(
    const ushort* __restrict__ qb, const ushort* __restrict__ kb,
    const ushort* __restrict__ vtb, ushort* __restrict__ outa)
{
  __shared__ ushort Ks[2][64*64];
  __shared__ ushort Vts[2][64*64];
  __shared__ ushort Ps[8*16*72];    // 4 waves x 2 subtiles

  int t = threadIdx.x;
  int lane = t & 63, w = t >> 6;
  int qt = blockIdx.x & 15;
  int h  = (blockIdx.x >> 4) & 7;
  int b  = blockIdx.x >> 7;
  int l0 = qt * 128;
  bool isgen = (l0 >= P_);
  int bh = b*H_ + h;

  const ushort* qg  = qb  + ((size_t)bh*L_ + l0)*DH_;
  const ushort* kgb = kb  + (size_t)bh*L_*DH_;
  const ushort* vtg = vtb + (size_t)bh*DH_*L_;

  int sr  = t >> 3;                       // staging row 0..31 (row+32 same &7)
  int scg = (t & 7) * 8;                  // global col (ushorts)
  int scs = ((t & 7) ^ (sr & 7)) * 8;     // swizzled LDS col

  int fr = lane & 15, fq = lane >> 4;
  int swz0 = ((0*4 + fq) ^ (fr & 7)) * 8; // fragment chunk, s=0
  int swz1 = ((1*4 + fq) ^ (fr & 7)) * 8; // fragment chunk, s=1

  // Q fragments: 2 subtiles x 2 k-halves
  bf16x8 qf[2][2];
  #pragma unroll
  for (int i=0;i<2;++i) {
    qf[i][0] = *(const bf16x8*)(qg + (size_t)(w*32 + i*16 + fr)*DH_ + fq*8);
    qf[i][1] = *(const bf16x8*)(qg + (size_t)(w*32 + i*16 + fr)*DH_ + 32 + fq*8);
  }

  float den[2][4] = {};
  f32x4 o[2][4] = {};
  ushort* Pw0 = Ps + (w*2 + 0)*16*72;
  ushort* Pw1 = Ps + (w*2 + 1)*16*72;

  // stage tile 0 into buffer 0 (linear global src, swizzled LDS dest)
  {
    uint4 a0 = *(const uint4*)(kgb + (size_t)sr*DH_ + scg);
    uint4 a1 = *(const uint4*)(kgb + (size_t)(sr+32)*DH_ + scg);
    uint4 a2 = *(const uint4*)(vtg + (size_t)sr*L_ + scg);
    uint4 a3 = *(const uint4*)(vtg + (size_t)(sr+32)*L_ + scg);
    *(uint4*)(&Ks[0][sr*64 + scs])       = a0;
    *(uint4*)(&Ks[0][(sr+32)*64 + scs])  = a1;
    *(uint4*)(&Vts[0][sr*64 + scs])      = a2;
    *(uint4*)(&Vts[0][(sr+32)*64 + scs]) = a3;
  }
  // register prefetch of tile 1
  uint4 pk0 = *(const uint4*)(kgb + (size_t)(64+sr)*DH_ + scg);
  uint4 pk1 = *(const uint4*)(kgb + (size_t)(64+sr+32)*DH_ + scg);
  uint4 pv0 = *(const uint4*)(vtg + (size_t)sr*L_ + 64 + scg);
  uint4 pv1 = *(const uint4*)(vtg + (size_t)(sr+32)*L_ + 64 + scg);
  __syncthreads();

  for (int kt = 0; kt < 16; ++kt) {
    const ushort* Kc = &Ks[kt & 1][0];
    const ushort* Vc = &Vts[kt & 1][0];
    if (kt < 15) {
      ushort* Kn = &Ks[(kt+1) & 1][0];
      ushort* Vn = &Vts[(kt+1) & 1][0];
      *(uint4*)(Kn + sr*64 + scs)      = pk0;
      *(uint4*)(Kn + (sr+32)*64 + scs) = pk1;
      *(uint4*)(Vn + sr*64 + scs)      = pv0;
      *(uint4*)(Vn + (sr+32)*64 + scs) = pv1;
    }
    if (kt < 14) {
      int p2 = (kt + 2) * 64;
      pk0 = *(const uint4*)(kgb + (size_t)(p2+sr)*DH_ + scg);
      pk1 = *(const uint4*)(kgb + (size_t)(p2+sr+32)*DH_ + scg);
      pv0 = *(const uint4*)(vtg + (size_t)sr*L_ + p2 + scg);
      pv1 = *(const uint4*)(vtg + (size_t)(sr+32)*L_ + p2 + scg);
    }

    f32x4 sc4[2][4] = {};
    __builtin_amdgcn_s_setprio(1);
    #pragma unroll
    for (int s=0;s<2;++s) {
      int sw = s ? swz1 : swz0;
      #pragma unroll
      for (int j=0;j<4;++j) {
        bf16x8 kf = *(const bf16x8*)(Kc + (j*16 + fr)*64 + sw);
        sc4[0][j] = __builtin_amdgcn_mfma_f32_16x16x32_bf16(qf[0][s], kf, sc4[0][j], 0, 0, 0);
        sc4[1][j] = __builtin_amdgcn_mfma_f32_16x16x32_bf16(qf[1][s], kf, sc4[1][j], 0, 0, 0);
      }
    }
    __builtin_amdgcn_s_setprio(0);

    #pragma unroll
    for (int i=0;i<2;++i) {
      ushort* Pw = i ? Pw1 : Pw0;
      #pragma unroll
      for (int r=0;r<4;++r) {
        float e0 = __expf(sc4[i][0][r]);
        float e1 = __expf(sc4[i][1][r]);
        float e2 = __expf(sc4[i][2][r]);
        float e3 = __expf(sc4[i][3][r]);
        den[i][r] += (e0+e1) + (e2+e3);
        Pw[(fq*4+r)*72 +  0 + fr] = (ushort)(__float_as_uint(e0) >> 16);
        Pw[(fq*4+r)*72 + 16 + fr] = (ushort)(__float_as_uint(e1) >> 16);
        Pw[(fq*4+r)*72 + 32 + fr] = (ushort)(__float_as_uint(e2) >> 16);
        Pw[(fq*4+r)*72 + 48 + fr] = (ushort)(__float_as_uint(e3) >> 16);
      }
    }
    asm volatile("s_waitcnt lgkmcnt(0)" ::: "memory");

    __builtin_amdgcn_s_setprio(1);
    #pragma unroll
    for (int s=0;s<2;++s) {
      int sw = s ? swz1 : swz0;
      bf16x8 pf0 = *(const bf16x8*)(Pw0 + fr*72 + s*32 + fq*8);
      bf16x8 pf1 = *(const bf16x8*)(Pw1 + fr*72 + s*32 + fq*8);
      #pragma unroll
      for (int j=0;j<4;++j) {
        bf16x8 vf = *(const bf16x8*)(Vc + (j*16 + fr)*64 + sw);
        o[0][j] = __builtin_amdgcn_mfma_f32_16x16x32_bf16(pf0, vf, o[0][j], 0, 0, 0);
        o[1][j] = __builtin_amdgcn_mfma_f32_16x16x32_bf16(pf1, vf, o[1][j], 0, 0, 0);
      }
    }
    __builtin_amdgcn_s_setprio(0);
    __syncthreads();
  }

  #pragma unroll
  for (int i=0;i<2;++i)
    #pragma unroll
    for (int r=0;r<4;++r) {
      float d = den[i][r];
      d += __shfl_xor(d, 1, 16);
      d += __shfl_xor(d, 2, 16);
      d += __shfl_xor(d, 4, 16);
      d += __shfl_xor(d, 8, 16);
      den[i][r] = d;
    }

  if (isgen) {
    // diagonal q.k via one 16x16 MFMA pair per subtile; diag S[m][m] lives in
    // lane fq*16+m (m = fq*4+r), register r. Broadcast with per-lane shfl.
    #pragma unroll
    for (int i=0;i<2;++i) {
      int base = l0 + w*32 + i*16;
      f32x4 dsc = {};
      {
        bf16x8 kd0 = *(const bf16x8*)(kgb + (size_t)(base + fr)*DH_ + fq*8);
        dsc = __builtin_amdgcn_mfma_f32_16x16x32_bf16(qf[i][0], kd0, dsc, 0, 0, 0);
        bf16x8 kd1 = *(const bf16x8*)(kgb + (size_t)(base + fr)*DH_ + 32 + fq*8);
        dsc = __builtin_amdgcn_mfma_f32_16x16x32_bf16(qf[i][1], kd1, dsc, 0, 0, 0);
      }
      #pragma unroll
      for (int r=0;r<4;++r) {
        int m = fq*4 + r;
        float dl = __shfl(dsc[r], fq*16 + m);
        float ed = __expf(dl);
        den[i][r] += ed;
        int l = base + m;
        #pragma unroll
        for (int j=0;j<4;++j) {
          float vv = b2f(vtg[(size_t)(j*16 + fr)*L_ + l]);
          o[i][j][r] += ed*vv;
        }
      }
    }
  }

  #pragma unroll
  for (int i=0;i<2;++i)
    #pragma unroll
    for (int r=0;r<4;++r) {
      float inv = 1.f / den[i][r];
      int l = l0 + w*32 + i*16 + fq*4 + r;
      #pragma unroll
      for (int j=0;j<4;++j)
        outa[((size_t)b*L_ + l)*D_ + h*DH_ + j*16 + fr] = f2b(o[i][j][r]*inv);
    }
}

// ---------------- LayerNorm -> x fp32 + xbf bf16 ----------------
__global__ __launch_bounds__(64) void ln_kernel(const float* __restrict__ y,
    const float* __restrict__ gw, const float* __restrict__ bw,
    float* __restrict__ x, ushort* __restrict__ xb)
{
  int row = blockIdx.x, t = threadIdx.x;
  const float4* yr = (const float4*)(y + (size_t)row*D_);
  float4 v0 = yr[t], v1 = yr[t+64];
  float s = v0.x+v0.y+v0.z+v0.w + v1.x+v1.y+v1.z+v1.w;
  for (int off=32; off>0; off>>=1) s += __shfl_down(s, off, 64);
  s = __shfl(s, 0, 64);
  float mu = s * (1.f/D_);
  float dx;
  float q = 0.f;
  dx=v0.x-mu; q+=dx*dx; dx=v0.y-mu; q+=dx*dx; dx=v0.z-mu; q+=dx*dx; dx=v0.w-mu; q+=dx*dx;
  dx=v1.x-mu; q+=dx*dx; dx=v1.y-mu; q+=dx*dx; dx=v1.z-mu; q+=dx*dx; dx=v1.w-mu; q+=dx*dx;
  for (int off=32; off>0; off>>=1) q += __shfl_down(q, off, 64);
  q = __shfl(q, 0, 64);
  float rinv = rsqrtf(q*(1.f/D_) + LN_EPS_);
  const float4* g4 = (const float4*)gw;
  const float4* b4 = (const float4*)bw;
  float4 gv0=g4[t], gv1=g4[t+64], bv0=b4[t], bv1=b4[t+64];
  float4 o0, o1;
  o0.x=(v0.x-mu)*rinv*gv0.x+bv0.x; o0.y=(v0.y-mu)*rinv*gv0.y+bv0.y;
  o0.z=(v0.z-mu)*rinv*gv0.z+bv0.z; o0.w=(v0.w-mu)*rinv*gv0.w+bv0.w;
  o1.x=(v1.x-mu)*rinv*gv1.x+bv1.x; o1.y=(v1.y-mu)*rinv*gv1.y+bv1.y;
  o1.z=(v1.z-mu)*rinv*gv1.z+bv1.z; o1.w=(v1.w-mu)*rinv*gv1.w+bv1.w;
  float4* xr = (float4*)(x + (size_t)row*D_);
  xr[t]=o0; xr[t+64]=o1;
  ushort4 h0, h1;
  h0.x=f2b(o0.x); h0.y=f2b(o0.y); h0.z=f2b(o0.z); h0.w=f2b(o0.w);
  h1.x=f2b(o1.x); h1.y=f2b(o1.y); h1.z=f2b(o1.z); h1.w=f2b(o1.w);
  ushort4* xbr = (ushort4*)(xb + (size_t)row*D_);
  xbr[t]=h0; xbr[t+64]=h1;
}

extern "C" void kernel_launch(void* const* d_in, const int* in_sizes, int n_in,
                              void* d_out, int out_size, void* d_ws, size_t ws_size,
                              hipStream_t stream) {
  const float* pcpt = (const float*)d_in[0];
  const float* gen  = (const float*)d_in[1];
  const float* Wqkv = (const float*)d_in[3];
  const float* bqkv = (const float*)d_in[4];
  const float* Wo   = (const float*)d_in[5];
  const float* bo   = (const float*)d_in[6];
  const float* W1   = (const float*)d_in[7];
  const float* b1   = (const float*)d_in[8];
  const float* W2   = (const float*)d_in[9];
  const float* b2   = (const float*)d_in[10];
  const float* g1   = (const float*)d_in[11];
  const float* be1  = (const float*)d_in[12];
  const float* g2   = (const float*)d_in[13];
  const float* be2  = (const float*)d_in[14];
  float* out = (float*)d_out;

  const size_t XD  = (size_t)B_*L_*D_;
  const size_t HKV = (size_t)B_*H_*L_*DH_;
  const size_t HFF = (size_t)B_*L_*FF_;

  float*  xbuf = (float*)d_ws;
  ushort* xbf  = (ushort*)(xbuf + XD);
  ushort* region = xbf + XD;
  ushort* qb  = region;                        // aliased with hbf
  ushort* kb  = region + HKV;
  ushort* vtb = region + 2*HKV;
  ushort* hbf = region;
  ushort* abf = region + HFF;
  ushort* wb  = abf + XD;
  ushort* wqkv_b = wb;
  ushort* wo_b   = wqkv_b + (size_t)4*3*D_*D_;
  ushort* w1_b   = wo_b   + (size_t)4*D_*D_;
  ushort* w2_b   = w1_b   + (size_t)4*FF_*D_;
  float*  ybuf = out;

  const int M = B_*L_;

  wconv_kernel<<<dim3(3*D_/32, D_/32, 4), 256, 0, stream>>>(Wqkv, wqkv_b, D_, 3*D_);
  wconv_kernel<<<dim3(D_/32,   D_/32, 4), 256, 0, stream>>>(Wo,   wo_b,   D_, D_);
  wconv_kernel<<<dim3(FF_/32,  D_/32, 4), 256, 0, stream>>>(W1,   w1_b,   D_, FF_);
  wconv_kernel<<<dim3(D_/32,  FF_/32, 4), 256, 0, stream>>>(W2,   w2_b,   FF_, D_);

  concat_kernel<<<4096, 256, 0, stream>>>(pcpt, gen, xbuf, xbf);

  for (int i = 0; i < LAYERS_; ++i) {
    const ushort* wqkv_i = wqkv_b + (size_t)i*3*D_*D_;
    const ushort* wo_i   = wo_b   + (size_t)i*D_*D_;
    const ushort* w1_i   = w1_b   + (size_t)i*FF_*D_;
    const ushort* w2_i   = w2_b   + (size_t)i*D_*FF_;
    const float* bqkv_i = bqkv + (size_t)i*3*D_;
    const float* bo_i   = bo   + (size_t)i*D_;
    const float* b1_i   = b1   + (size_t)i*FF_;
    const float* b2_i   = b2   + (size_t)i*D_;
    const float* g1_i   = g1   + (size_t)i*D_;
    const float* be1_i  = be1  + (size_t)i*D_;
    const float* g2_i   = g2   + (size_t)i*D_;
    const float* be2_i  = be2  + (size_t)i*D_;

    // grid: (m-tiles, n-tiles) -> n-tiles of an m-band share an XCD
    mgemm_qkv<<<dim3(M/128, 3*D_/128), 256, 0, stream>>>(
        xbf, wqkv_i, bqkv_i, qb, kb, vtb);

    attn_mfma<<<B_*H_*(L_/128), 256, 0, stream>>>(qb, kb, vtb, abf);

    mgemm<64,0,1,0><<<dim3(M/128, D_/64), 256, 0, stream>>>(
        abf, wo_i, bo_i, xbuf, ybuf, M, D_, D_);

    ln_kernel<<<M, 64, 0, stream>>>(ybuf, g1_i, be1_i, xbuf, xbf);

    mgemm<128,1,0,1><<<dim3(M/128, FF_/128), 256, 0, stream>>>(
        xbf, w1_i, b1_i, nullptr, hbf, M, FF_, D_);

    mgemm<64,0,1,0><<<dim3(M/128, D_/64), 256, 0, stream>>>(
        hbf, w2_i, b2_i, xbuf, ybuf, M, D_, FF_);

    ln_kernel<<<M, 64, 0, stream>>>(ybuf, g2_i, be2_i, xbuf, xbf);
  }

  writeout_kernel<<<4096, 256, 0, stream>>>(xbuf, out);
}

// Round 7
// 711.955 us; speedup vs baseline: 1.1068x; 1.0554x over previous
//
#include <hip/hip_runtime.h>
#include <hip/hip_bf16.h>

#define B_ 4
#define P_ 1024
#define G_ 1024
#define L_ 2048
#define D_ 512
#define FF_ 2048
#define H_ 8
#define DH_ 64
#define LAYERS_ 4
#define LN_EPS_ 1e-5f

typedef __attribute__((ext_vector_type(8))) short bf16x8;
typedef __attribute__((ext_vector_type(4))) float f32x4;

__device__ __forceinline__ ushort f2b(float f) {
  unsigned u = __float_as_uint(f);
  unsigned r = (u + 0x7fffu + ((u >> 16) & 1u)) >> 16;
  return (ushort)r;
}
__device__ __forceinline__ float b2f(ushort u) {
  return __uint_as_float(((unsigned)u) << 16);
}

// async 16B global->LDS (DMA; dest = wave-uniform base + lane*16)
__device__ __forceinline__ void gld16(const ushort* g, ushort* l) {
  __builtin_amdgcn_global_load_lds(
      (const __attribute__((address_space(1))) void*)g,
      (__attribute__((address_space(3))) void*)l, 16, 0, 0);
}

// ---------------- concat pcpt+gen -> x (fp32) + xbf (bf16) ----------------
__global__ __launch_bounds__(256) void concat_kernel(const float* __restrict__ p,
    const float* __restrict__ g, float* __restrict__ x, ushort* __restrict__ xb)
{
  const int LD4 = L_*D_/4, PD4 = P_*D_/4;
  int i = blockIdx.x*256 + threadIdx.x;
  int b = i / LD4, r = i - b*LD4;
  float4 v;
  if (r < PD4) v = ((const float4*)p)[(size_t)b*PD4 + r];
  else         v = ((const float4*)g)[(size_t)b*PD4 + (r-PD4)];
  ((float4*)x)[i] = v;
  ushort4 h; h.x=f2b(v.x); h.y=f2b(v.y); h.z=f2b(v.z); h.w=f2b(v.w);
  ((ushort4*)xb)[i] = h;
}

// ---------------- weight transpose+convert: src K x N fp32 -> dst N x K bf16 ----------------
__global__ __launch_bounds__(256) void wconv_kernel(const float* __restrict__ src,
    ushort* __restrict__ dst, int K, int N)
{
  __shared__ float tile[32][33];
  int n0 = blockIdx.x*32, k0 = blockIdx.y*32, l = blockIdx.z;
  src += (size_t)l*K*N; dst += (size_t)l*K*N;
  int tx = threadIdx.x & 31, ty = threadIdx.x >> 5;
  #pragma unroll
  for (int u=0;u<4;++u) tile[ty+8*u][tx] = src[(size_t)(k0+ty+8*u)*N + n0+tx];
  __syncthreads();
  #pragma unroll
  for (int u=0;u<4;++u) dst[(size_t)(n0+ty+8*u)*K + k0+tx] = f2b(tile[tx][ty+8*u]);
}

// ---------------- bf16 MFMA GEMM, 2-phase prefetch pipeline (r4-best) -------
// Per K-step: vmcnt(0); s_barrier; sched_barrier; STAGE(next, other buf);
// compute(cur).
template<int BN_, int RELU, int RES, int OUTBF>
__global__ __launch_bounds__(256) void mgemm(
    const ushort* __restrict__ A, const ushort* __restrict__ Bt,
    const float* __restrict__ bias, const float* __restrict__ res,
    void* __restrict__ Cout, int M, int N, int K)
{
  constexpr int MI = (BN_ == 128) ? 4 : 2;
  constexpr int BL = BN_ / 32;               // B loader row-groups
  __shared__ ushort As[2*128*64];
  __shared__ ushort Bs[2*BN_*64];
  int t = threadIdx.x;
  int lane = t & 63, w = t >> 6;
  int wm = (BN_ == 128) ? (w >> 1) * 64 : w * 32;
  int wn = (BN_ == 128) ? (w & 1) * 64 : 0;
  int m0 = blockIdx.x * 128, n0 = blockIdx.y * BN_;

  f32x4 acc[MI][4] = {};

  int rbase = t >> 3;                        // 0..31
  int cch   = (t & 7) ^ ((t >> 3) & 7);      // swizzled chunk col (L-invariant)
  const ushort* Ag = A  + (size_t)(m0 + rbase)*K + cch*8;
  const ushort* Bg = Bt + (size_t)(n0 + rbase)*K + cch*8;
  ushort* Asl0 = As + t*8;
  ushort* Asl1 = As + 128*64 + t*8;
  ushort* Bsl0 = Bs + t*8;
  ushort* Bsl1 = Bs + BN_*64 + t*8;
  const size_t rowK32 = (size_t)32 * K;

  int fr = lane & 15, fq = lane >> 4;
  int swr[2];
  swr[0] = ((0*4 + fq) ^ (fr & 7)) * 8;
  swr[1] = ((1*4 + fq) ^ (fr & 7)) * 8;

  // prologue: stage tile 0 into buffer 0
  #pragma unroll
  for (int L = 0; L < 4; ++L)  gld16(Ag + L*rowK32, Asl0 + L*2048);
  #pragma unroll
  for (int L = 0; L < BL; ++L) gld16(Bg + L*rowK32, Bsl0 + L*2048);

  const int NT = K >> 6;
  for (int tt = 0; tt < NT; ++tt) {
    asm volatile("s_waitcnt vmcnt(0)" ::: "memory");
    __builtin_amdgcn_s_barrier();
    __builtin_amdgcn_sched_barrier(0);
    if (tt + 1 < NT) {
      const ushort* Agn = Ag + (size_t)(tt+1)*64;
      const ushort* Bgn = Bg + (size_t)(tt+1)*64;
      ushort* Ad = (tt & 1) ? Asl0 : Asl1;   // tile tt+1 -> buffer (tt+1)&1
      ushort* Bd = (tt & 1) ? Bsl0 : Bsl1;
      #pragma unroll
      for (int L = 0; L < 4; ++L)  gld16(Agn + L*rowK32, Ad + L*2048);
      #pragma unroll
      for (int L = 0; L < BL; ++L) gld16(Bgn + L*rowK32, Bd + L*2048);
    }
    const ushort* Ard = ((tt & 1) ? As + 128*64 : As) + (wm + fr)*64;
    const ushort* Brd = ((tt & 1) ? Bs + BN_*64 : Bs) + (wn + fr)*64;
    #pragma unroll
    for (int s = 0; s < 2; ++s) {
      int sw = swr[s];
      bf16x8 af[MI], bfr[4];
      #pragma unroll
      for (int i=0;i<MI;++i) af[i]  = *(const bf16x8*)(Ard + i*16*64 + sw);
      #pragma unroll
      for (int j=0;j<4;++j)  bfr[j] = *(const bf16x8*)(Brd + j*16*64 + sw);
      #pragma unroll
      for (int i=0;i<MI;++i)
        #pragma unroll
        for (int j=0;j<4;++j)
          acc[i][j] = __builtin_amdgcn_mfma_f32_16x16x32_bf16(af[i], bfr[j], acc[i][j], 0, 0, 0);
    }
  }

  int ncol = lane & 15;
  int rquad = (lane >> 4) * 4;
  #pragma unroll
  for (int j=0;j<4;++j) {
    int n = n0 + wn + j*16 + ncol;
    float bv = bias[n];
    #pragma unroll
    for (int i=0;i<MI;++i) {
      int mbase = m0 + wm + i*16 + rquad;
      #pragma unroll
      for (int r=0;r<4;++r) {
        int m = mbase + r;
        float c = acc[i][j][r] + bv;
        if (RES) c += res[(size_t)m*N + n];
        if (RELU) c = fmaxf(c, 0.f);
        if (OUTBF) ((ushort*)Cout)[(size_t)m*N + n] = f2b(c);
        else       ((float*)Cout)[(size_t)m*N + n] = c;
      }
    }
  }
}

// ---------------- QKV GEMM, 2-phase pipeline + LDS-transposed v store -------
__global__ __launch_bounds__(256) void mgemm_qkv(
    const ushort* __restrict__ A,    // M x 512 bf16 (x)
    const ushort* __restrict__ Bt,   // 1536 x 512 bf16
    const float* __restrict__ bias,  // 1536
    ushort* __restrict__ qb,         // [b,h,l,64]  (pre-scaled by 0.125)
    ushort* __restrict__ kb,         // [b,h,l,64]
    ushort* __restrict__ vtb)        // [b,h,64,l]
{
  const int K = D_;
  __shared__ ushort SMEM[4*128*64];     // As dbuf | Bs dbuf; reused as T
  ushort* As = SMEM;
  ushort* Bs = SMEM + 2*128*64;
  int t = threadIdx.x;
  int lane = t & 63, w = t >> 6;
  int wm = (w >> 1) * 64, wn = (w & 1) * 64;
  int m0 = blockIdx.x * 128, n0 = blockIdx.y * 128;

  f32x4 acc[4][4] = {};

  int rbase = t >> 3;
  int cch   = (t & 7) ^ ((t >> 3) & 7);
  const ushort* Ag = A  + (size_t)(m0 + rbase)*K + cch*8;
  const ushort* Bg = Bt + (size_t)(n0 + rbase)*K + cch*8;
  ushort* Asl0 = As + t*8;
  ushort* Asl1 = As + 128*64 + t*8;
  ushort* Bsl0 = Bs + t*8;
  ushort* Bsl1 = Bs + 128*64 + t*8;
  const size_t rowK32 = (size_t)32 * K;

  int fr = lane & 15, fq = lane >> 4;
  int swr[2];
  swr[0] = ((0*4 + fq) ^ (fr & 7)) * 8;
  swr[1] = ((1*4 + fq) ^ (fr & 7)) * 8;

  // prologue: stage tile 0 into buffer 0
  #pragma unroll
  for (int L = 0; L < 4; ++L) gld16(Ag + L*rowK32, Asl0 + L*2048);
  #pragma unroll
  for (int L = 0; L < 4; ++L) gld16(Bg + L*rowK32, Bsl0 + L*2048);

  const int NT = K >> 6;
  for (int tt = 0; tt < NT; ++tt) {
    asm volatile("s_waitcnt vmcnt(0)" ::: "memory");
    __builtin_amdgcn_s_barrier();
    __builtin_amdgcn_sched_barrier(0);
    if (tt + 1 < NT) {
      const ushort* Agn = Ag + (size_t)(tt+1)*64;
      const ushort* Bgn = Bg + (size_t)(tt+1)*64;
      ushort* Ad = (tt & 1) ? Asl0 : Asl1;
      ushort* Bd = (tt & 1) ? Bsl0 : Bsl1;
      #pragma unroll
      for (int L = 0; L < 4; ++L) gld16(Agn + L*rowK32, Ad + L*2048);
      #pragma unroll
      for (int L = 0; L < 4; ++L) gld16(Bgn + L*rowK32, Bd + L*2048);
    }
    const ushort* Ard = ((tt & 1) ? As + 128*64 : As) + (wm + fr)*64;
    const ushort* Brd = ((tt & 1) ? Bs + 128*64 : Bs) + (wn + fr)*64;
    #pragma unroll
    for (int s = 0; s < 2; ++s) {
      int sw = swr[s];
      bf16x8 af[4], bfr[4];
      #pragma unroll
      for (int i=0;i<4;++i) af[i]  = *(const bf16x8*)(Ard + i*16*64 + sw);
      #pragma unroll
      for (int j=0;j<4;++j) bfr[j] = *(const bf16x8*)(Brd + j*16*64 + sw);
      #pragma unroll
      for (int i=0;i<4;++i)
        #pragma unroll
        for (int j=0;j<4;++j)
          acc[i][j] = __builtin_amdgcn_mfma_f32_16x16x32_bf16(af[i], bfr[j], acc[i][j], 0, 0, 0);
    }
  }

  int ncol = lane & 15;
  int rquad = (lane >> 4) * 4;

  if (n0 < 1024) {
    // ---- q/k path: 32B-chunk coalesced scalar stores (unchanged) ----
    #pragma unroll
    for (int j=0;j<4;++j) {
      int n = n0 + wn + j*16 + ncol;
      float bv = bias[n];
      int part = n >> 9;            // 0=q 1=k (block-uniform)
      int wi = n & 511;
      int h = wi >> 6, d = wi & 63;
      #pragma unroll
      for (int i=0;i<4;++i) {
        int mbase = m0 + wm + i*16 + rquad;
        #pragma unroll
        for (int r=0;r<4;++r) {
          int m = mbase + r;
          int b = m >> 11, l = m & 2047;
          int bh = b*H_ + h;
          float cv = acc[i][j][r] + bv;
          if (part == 0) cv *= 0.125f;       // fold 1/sqrt(dh) into q
          ushort c = f2b(cv);
          if (part == 0) qb[((size_t)bh*L_ + l)*DH_ + d] = c;
          else           kb[((size_t)bh*L_ + l)*DH_ + d] = c;
        }
      }
    }
  } else {
    // ---- v path: transpose via LDS, coalesced 16B stores along l ----
    __syncthreads();                   // all waves done reading As/Bs
    ushort* T = SMEM;                  // [128 nrel][136] (pad 8)
    #pragma unroll
    for (int j=0;j<4;++j) {
      int nrel = wn + j*16 + ncol;
      float bv = bias[n0 + nrel];
      #pragma unroll
      for (int i=0;i<4;++i) {
        #pragma unroll
        for (int r=0;r<4;++r) {
          int mrel = wm + i*16 + rquad + r;
          T[nrel*136 + mrel] = f2b(acc[i][j][r] + bv);
        }
      }
    }
    __syncthreads();
    int b = m0 >> 11, l0r = m0 & 2047;
    int wi0 = n0 & 511;
    #pragma unroll
    for (int u = 0; u < 8; ++u) {
      int idx = u*256 + t;             // 0..2047
      int row = idx >> 4, mc = idx & 15;
      uint4 val = *(const uint4*)(T + row*136 + mc*8);
      int wi = wi0 + row;
      int h = wi >> 6, d = wi & 63;
      int bh = b*H_ + h;
      *(uint4*)(vtb + ((size_t)bh*DH_ + d)*L_ + l0r + mc*8) = val;
    }
  }
}

// ---------------- MFMA flash attention: QBLK=128, swizzled K/V LDS ----------
__global__ __launch_bounds__(256) void attn_mfma(
    const ushort* __restrict__ qb, const ushort* __restrict__ kb,
    const ushort* __restrict__ vtb, ushort* __restrict__ outa)
{
  __shared__ ushort Ks[2][64*64];
  __shared__ ushort Vts[2][64*64];
  __shared__ ushort Ps[8*16*72];    // 4 waves x 2 subtiles

  int t = threadIdx.x;
  int lane = t & 63, w = t >> 6;
  int qt = blockIdx.x & 15;
  int h  = (blockIdx.x >> 4) & 7;
  int b  = blockIdx.x >> 7;
  int l0 = qt * 128;
  bool isgen = (l0 >= P_);
  int bh = b*H_ + h;

  const ushort* qg  = qb  + ((size_t)bh*L_ + l0)*DH_;
  const ushort* kgb = kb  + (size_t)bh*L_*DH_;
  const ushort* vtg = vtb + (size_t)bh*DH_*L_;

  int sr  = t >> 3;                       // staging row 0..31 (row+32 same &7)
  int scg = (t & 7) * 8;                  // global col (ushorts)
  int scs = ((t & 7) ^ (sr & 7)) * 8;     // swizzled LDS col

  int fr = lane & 15, fq = lane >> 4;
  int swz0 = ((0*4 + fq) ^ (fr & 7)) * 8; // fragment chunk, s=0
  int swz1 = ((1*4 + fq) ^ (fr & 7)) * 8; // fragment chunk, s=1

  // Q fragments: 2 subtiles x 2 k-halves
  bf16x8 qf[2][2];
  #pragma unroll
  for (int i=0;i<2;++i) {
    qf[i][0] = *(const bf16x8*)(qg + (size_t)(w*32 + i*16 + fr)*DH_ + fq*8);
    qf[i][1] = *(const bf16x8*)(qg + (size_t)(w*32 + i*16 + fr)*DH_ + 32 + fq*8);
  }

  float den[2][4] = {};
  f32x4 o[2][4] = {};
  ushort* Pw0 = Ps + (w*2 + 0)*16*72;
  ushort* Pw1 = Ps + (w*2 + 1)*16*72;

  // stage tile 0 into buffer 0 (linear global src, swizzled LDS dest)
  {
    uint4 a0 = *(const uint4*)(kgb + (size_t)sr*DH_ + scg);
    uint4 a1 = *(const uint4*)(kgb + (size_t)(sr+32)*DH_ + scg);
    uint4 a2 = *(const uint4*)(vtg + (size_t)sr*L_ + scg);
    uint4 a3 = *(const uint4*)(vtg + (size_t)(sr+32)*L_ + scg);
    *(uint4*)(&Ks[0][sr*64 + scs])       = a0;
    *(uint4*)(&Ks[0][(sr+32)*64 + scs])  = a1;
    *(uint4*)(&Vts[0][sr*64 + scs])      = a2;
    *(uint4*)(&Vts[0][(sr+32)*64 + scs]) = a3;
  }
  // register prefetch of tile 1
  uint4 pk0 = *(const uint4*)(kgb + (size_t)(64+sr)*DH_ + scg);
  uint4 pk1 = *(const uint4*)(kgb + (size_t)(64+sr+32)*DH_ + scg);
  uint4 pv0 = *(const uint4*)(vtg + (size_t)sr*L_ + 64 + scg);
  uint4 pv1 = *(const uint4*)(vtg + (size_t)(sr+32)*L_ + 64 + scg);
  __syncthreads();

  for (int kt = 0; kt < 16; ++kt) {
    const ushort* Kc = &Ks[kt & 1][0];
    const ushort* Vc = &Vts[kt & 1][0];
    if (kt < 15) {
      ushort* Kn = &Ks[(kt+1) & 1][0];
      ushort* Vn = &Vts[(kt+1) & 1][0];
      *(uint4*)(Kn + sr*64 + scs)      = pk0;
      *(uint4*)(Kn + (sr+32)*64 + scs) = pk1;
      *(uint4*)(Vn + sr*64 + scs)      = pv0;
      *(uint4*)(Vn + (sr+32)*64 + scs) = pv1;
    }
    if (kt < 14) {
      int p2 = (kt + 2) * 64;
      pk0 = *(const uint4*)(kgb + (size_t)(p2+sr)*DH_ + scg);
      pk1 = *(const uint4*)(kgb + (size_t)(p2+sr+32)*DH_ + scg);
      pv0 = *(const uint4*)(vtg + (size_t)sr*L_ + p2 + scg);
      pv1 = *(const uint4*)(vtg + (size_t)(sr+32)*L_ + p2 + scg);
    }

    f32x4 sc4[2][4] = {};
    __builtin_amdgcn_s_setprio(1);
    #pragma unroll
    for (int s=0;s<2;++s) {
      int sw = s ? swz1 : swz0;
      #pragma unroll
      for (int j=0;j<4;++j) {
        bf16x8 kf = *(const bf16x8*)(Kc + (j*16 + fr)*64 + sw);
        sc4[0][j] = __builtin_amdgcn_mfma_f32_16x16x32_bf16(qf[0][s], kf, sc4[0][j], 0, 0, 0);
        sc4[1][j] = __builtin_amdgcn_mfma_f32_16x16x32_bf16(qf[1][s], kf, sc4[1][j], 0, 0, 0);
      }
    }
    __builtin_amdgcn_s_setprio(0);

    #pragma unroll
    for (int i=0;i<2;++i) {
      ushort* Pw = i ? Pw1 : Pw0;
      #pragma unroll
      for (int r=0;r<4;++r) {
        float e0 = __expf(sc4[i][0][r]);
        float e1 = __expf(sc4[i][1][r]);
        float e2 = __expf(sc4[i][2][r]);
        float e3 = __expf(sc4[i][3][r]);
        den[i][r] += (e0+e1) + (e2+e3);
        Pw[(fq*4+r)*72 +  0 + fr] = (ushort)(__float_as_uint(e0) >> 16);
        Pw[(fq*4+r)*72 + 16 + fr] = (ushort)(__float_as_uint(e1) >> 16);
        Pw[(fq*4+r)*72 + 32 + fr] = (ushort)(__float_as_uint(e2) >> 16);
        Pw[(fq*4+r)*72 + 48 + fr] = (ushort)(__float_as_uint(e3) >> 16);
      }
    }
    asm volatile("s_waitcnt lgkmcnt(0)" ::: "memory");

    __builtin_amdgcn_s_setprio(1);
    #pragma unroll
    for (int s=0;s<2;++s) {
      int sw = s ? swz1 : swz0;
      bf16x8 pf0 = *(const bf16x8*)(Pw0 + fr*72 + s*32 + fq*8);
      bf16x8 pf1 = *(const bf16x8*)(Pw1 + fr*72 + s*32 + fq*8);
      #pragma unroll
      for (int j=0;j<4;++j) {
        bf16x8 vf = *(const bf16x8*)(Vc + (j*16 + fr)*64 + sw);
        o[0][j] = __builtin_amdgcn_mfma_f32_16x16x32_bf16(pf0, vf, o[0][j], 0, 0, 0);
        o[1][j] = __builtin_amdgcn_mfma_f32_16x16x32_bf16(pf1, vf, o[1][j], 0, 0, 0);
      }
    }
    __builtin_amdgcn_s_setprio(0);
    __syncthreads();
  }

  #pragma unroll
  for (int i=0;i<2;++i)
    #pragma unroll
    for (int r=0;r<4;++r) {
      float d = den[i][r];
      d += __shfl_xor(d, 1, 16);
      d += __shfl_xor(d, 2, 16);
      d += __shfl_xor(d, 4, 16);
      d += __shfl_xor(d, 8, 16);
      den[i][r] = d;
    }

  if (isgen) {
    // diagonal q.k via one 16x16 MFMA pair per subtile; diag S[m][m] lives in
    // lane fq*16+m (m = fq*4+r), register r. Broadcast with per-lane shfl.
    #pragma unroll
    for (int i=0;i<2;++i) {
      int base = l0 + w*32 + i*16;
      f32x4 dsc = {};
      {
        bf16x8 kd0 = *(const bf16x8*)(kgb + (size_t)(base + fr)*DH_ + fq*8);
        dsc = __builtin_amdgcn_mfma_f32_16x16x32_bf16(qf[i][0], kd0, dsc, 0, 0, 0);
        bf16x8 kd1 = *(const bf16x8*)(kgb + (size_t)(base + fr)*DH_ + 32 + fq*8);
        dsc = __builtin_amdgcn_mfma_f32_16x16x32_bf16(qf[i][1], kd1, dsc, 0, 0, 0);
      }
      #pragma unroll
      for (int r=0;r<4;++r) {
        int m = fq*4 + r;
        float dl = __shfl(dsc[r], fq*16 + m);
        float ed = __expf(dl);
        den[i][r] += ed;
        int l = base + m;
        #pragma unroll
        for (int j=0;j<4;++j) {
          float vv = b2f(vtg[(size_t)(j*16 + fr)*L_ + l]);
          o[i][j][r] += ed*vv;
        }
      }
    }
  }

  #pragma unroll
  for (int i=0;i<2;++i)
    #pragma unroll
    for (int r=0;r<4;++r) {
      float inv = 1.f / den[i][r];
      int l = l0 + w*32 + i*16 + fq*4 + r;
      #pragma unroll
      for (int j=0;j<4;++j)
        outa[((size_t)b*L_ + l)*D_ + h*DH_ + j*16 + fr] = f2b(o[i][j][r]*inv);
    }
}

// ---------------- LayerNorm: 4 rows/block (1 row/wave) -----------------------
// FINAL=0: write x fp32 + xbf bf16 (layer-internal).
// FINAL=1: write directly to out with the pcpt/gen split permutation and skip
//          x/xbf entirely -- replaces the old writeout_kernel (saves a 32MB
//          round trip + 24MB of dead x writes on the last layer).
// 4-wave blocks: 2048 blocks instead of 8192 1-wave blocks (workgroup-slot
// cap made 1-wave blocks max out at 16 waves/CU; 4-wave blocks reach 32).
template<int FINAL>
__global__ __launch_bounds__(256) void ln_kernel(const float* __restrict__ y,
    const float* __restrict__ gw, const float* __restrict__ bw,
    float* __restrict__ x, ushort* __restrict__ xb, float* __restrict__ outf)
{
  int w = threadIdx.x >> 6, t = threadIdx.x & 63;
  int row = blockIdx.x*4 + w;
  const float4* yr = (const float4*)(y + (size_t)row*D_);
  float4 v0 = yr[t], v1 = yr[t+64];
  float s = v0.x+v0.y+v0.z+v0.w + v1.x+v1.y+v1.z+v1.w;
  for (int off=32; off>0; off>>=1) s += __shfl_down(s, off, 64);
  s = __shfl(s, 0, 64);
  float mu = s * (1.f/D_);
  float dx;
  float q = 0.f;
  dx=v0.x-mu; q+=dx*dx; dx=v0.y-mu; q+=dx*dx; dx=v0.z-mu; q+=dx*dx; dx=v0.w-mu; q+=dx*dx;
  dx=v1.x-mu; q+=dx*dx; dx=v1.y-mu; q+=dx*dx; dx=v1.z-mu; q+=dx*dx; dx=v1.w-mu; q+=dx*dx;
  for (int off=32; off>0; off>>=1) q += __shfl_down(q, off, 64);
  q = __shfl(q, 0, 64);
  float rinv = rsqrtf(q*(1.f/D_) + LN_EPS_);
  const float4* g4 = (const float4*)gw;
  const float4* b4 = (const float4*)bw;
  float4 gv0=g4[t], gv1=g4[t+64], bv0=b4[t], bv1=b4[t+64];
  float4 o0, o1;
  o0.x=(v0.x-mu)*rinv*gv0.x+bv0.x; o0.y=(v0.y-mu)*rinv*gv0.y+bv0.y;
  o0.z=(v0.z-mu)*rinv*gv0.z+bv0.z; o0.w=(v0.w-mu)*rinv*gv0.w+bv0.w;
  o1.x=(v1.x-mu)*rinv*gv1.x+bv1.x; o1.y=(v1.y-mu)*rinv*gv1.y+bv1.y;
  o1.z=(v1.z-mu)*rinv*gv1.z+bv1.z; o1.w=(v1.w-mu)*rinv*gv1.w+bv1.w;
  if (FINAL) {
    int b = row >> 11, l = row & 2047;
    int orow = (l < P_) ? (b*P_ + l) : (B_*P_ + b*G_ + (l - P_));
    float4* orp = (float4*)(outf + (size_t)orow*D_);
    orp[t] = o0; orp[t+64] = o1;
  } else {
    float4* xr = (float4*)(x + (size_t)row*D_);
    xr[t]=o0; xr[t+64]=o1;
    ushort4 h0, h1;
    h0.x=f2b(o0.x); h0.y=f2b(o0.y); h0.z=f2b(o0.z); h0.w=f2b(o0.w);
    h1.x=f2b(o1.x); h1.y=f2b(o1.y); h1.z=f2b(o1.z); h1.w=f2b(o1.w);
    ushort4* xbr = (ushort4*)(xb + (size_t)row*D_);
    xbr[t]=h0; xbr[t+64]=h1;
  }
}

extern "C" void kernel_launch(void* const* d_in, const int* in_sizes, int n_in,
                              void* d_out, int out_size, void* d_ws, size_t ws_size,
                              hipStream_t stream) {
  const float* pcpt = (const float*)d_in[0];
  const float* gen  = (const float*)d_in[1];
  const float* Wqkv = (const float*)d_in[3];
  const float* bqkv = (const float*)d_in[4];
  const float* Wo   = (const float*)d_in[5];
  const float* bo   = (const float*)d_in[6];
  const float* W1   = (const float*)d_in[7];
  const float* b1   = (const float*)d_in[8];
  const float* W2   = (const float*)d_in[9];
  const float* b2   = (const float*)d_in[10];
  const float* g1   = (const float*)d_in[11];
  const float* be1  = (const float*)d_in[12];
  const float* g2   = (const float*)d_in[13];
  const float* be2  = (const float*)d_in[14];
  float* out = (float*)d_out;

  const size_t XD  = (size_t)B_*L_*D_;
  const size_t HKV = (size_t)B_*H_*L_*DH_;
  const size_t HFF = (size_t)B_*L_*FF_;

  float*  xbuf = (float*)d_ws;
  ushort* xbf  = (ushort*)(xbuf + XD);
  ushort* region = xbf + XD;
  ushort* qb  = region;                        // aliased with hbf
  ushort* kb  = region + HKV;
  ushort* vtb = region + 2*HKV;
  ushort* hbf = region;
  ushort* abf = region + HFF;
  ushort* wb  = abf + XD;
  ushort* wqkv_b = wb;
  ushort* wo_b   = wqkv_b + (size_t)4*3*D_*D_;
  ushort* w1_b   = wo_b   + (size_t)4*D_*D_;
  ushort* w2_b   = w1_b   + (size_t)4*FF_*D_;
  float*  ybuf = out;

  const int M = B_*L_;

  wconv_kernel<<<dim3(3*D_/32, D_/32, 4), 256, 0, stream>>>(Wqkv, wqkv_b, D_, 3*D_);
  wconv_kernel<<<dim3(D_/32,   D_/32, 4), 256, 0, stream>>>(Wo,   wo_b,   D_, D_);
  wconv_kernel<<<dim3(FF_/32,  D_/32, 4), 256, 0, stream>>>(W1,   w1_b,   D_, FF_);
  wconv_kernel<<<dim3(D_/32,  FF_/32, 4), 256, 0, stream>>>(W2,   w2_b,   FF_, D_);

  concat_kernel<<<4096, 256, 0, stream>>>(pcpt, gen, xbuf, xbf);

  for (int i = 0; i < LAYERS_; ++i) {
    const ushort* wqkv_i = wqkv_b + (size_t)i*3*D_*D_;
    const ushort* wo_i   = wo_b   + (size_t)i*D_*D_;
    const ushort* w1_i   = w1_b   + (size_t)i*FF_*D_;
    const ushort* w2_i   = w2_b   + (size_t)i*D_*FF_;
    const float* bqkv_i = bqkv + (size_t)i*3*D_;
    const float* bo_i   = bo   + (size_t)i*D_;
    const float* b1_i   = b1   + (size_t)i*FF_;
    const float* b2_i   = b2   + (size_t)i*D_;
    const float* g1_i   = g1   + (size_t)i*D_;
    const float* be1_i  = be1  + (size_t)i*D_;
    const float* g2_i   = g2   + (size_t)i*D_;
    const float* be2_i  = be2  + (size_t)i*D_;

    // grid: (m-tiles, n-tiles) -> n-tiles of an m-band share an XCD
    mgemm_qkv<<<dim3(M/128, 3*D_/128), 256, 0, stream>>>(
        xbf, wqkv_i, bqkv_i, qb, kb, vtb);

    attn_mfma<<<B_*H_*(L_/128), 256, 0, stream>>>(qb, kb, vtb, abf);

    mgemm<64,0,1,0><<<dim3(M/128, D_/64), 256, 0, stream>>>(
        abf, wo_i, bo_i, xbuf, ybuf, M, D_, D_);

    ln_kernel<0><<<M/4, 256, 0, stream>>>(ybuf, g1_i, be1_i, xbuf, xbf, nullptr);

    mgemm<128,1,0,1><<<dim3(M/128, FF_/128), 256, 0, stream>>>(
        xbf, w1_i, b1_i, nullptr, hbf, M, FF_, D_);

    mgemm<64,0,1,0><<<dim3(M/128, D_/64), 256, 0, stream>>>(
        hbf, w2_i, b2_i, xbuf, ybuf, M, D_, FF_);

    if (i == LAYERS_-1)
      ln_kernel<1><<<M/4, 256, 0, stream>>>(ybuf, g2_i, be2_i, nullptr, nullptr, out);
    else
      ln_kernel<0><<<M/4, 256, 0, stream>>>(ybuf, g2_i, be2_i, xbuf, xbf, nullptr);
  }
}